// Round 4
// baseline (462.401 us; speedup 1.0000x reference)
//
#include <hip/hip_runtime.h>
#include <hip/hip_bf16.h>

typedef __attribute__((ext_vector_type(8)))  short short8;
typedef __attribute__((ext_vector_type(16))) float f32x16;
typedef unsigned short u16;
typedef unsigned int   u32;

__device__ __forceinline__ u16 f2b(float f){
    __hip_bfloat16 h = __float2bfloat16(f);
    u16 u; __builtin_memcpy(&u, &h, 2); return u;
}
__device__ __forceinline__ u32 pk2(float lo, float hi){
    return (u32)f2b(lo) | ((u32)f2b(hi) << 16);
}
__device__ __forceinline__ float b2f(u16 u){
    u32 w = ((u32)u) << 16; float f; __builtin_memcpy(&f, &w, 4); return f;
}

#define PART_STRIDE 8448  // 64*128B bf16 O^T + 32 f32 m + 32 f32 l (16B-aligned)

// S=2048, H=32, HKV=8, G=4, D=128, DIFF_BS=32
// Split-KV flash-decode: block = (kv-head, q-tile, kv-chunk of 512 keys).
// 4 waves = 4 GQA query heads. Swapped QK^T / PV as in R3 (verified math).
// Chunked blocks write unnormalized bf16 O^T partials + (m,l); merge kernel
// combines. tq<16 (single chunk) writes output directly.
template<bool SPLIT>
__global__ __launch_bounds__(256, 4)
void dllm_attn(const float* __restrict__ Qg, const float* __restrict__ Kg,
               const float* __restrict__ Vg, float* __restrict__ Og,
               char* __restrict__ Wg)
{
    __shared__ alignas(16) char kl[64 * 256];   // K tile bf16 [64][128], XOR-swizzled
    __shared__ alignas(16) char vl[128 * 128];  // V^T tile bf16 [128][64], XOR-swizzled

    const int bid = blockIdx.x;
    const int kh  = bid & 7;
    int tq, ci, uu = 0;
    if (SPLIT){
        uu = 159 - (bid >> 3);                  // big tiles first
        if (uu < 16)      { tq = uu; ci = 0; }
        else if (uu < 48) { const int x = uu - 16; tq = 16 + (x >> 1); ci = x & 1; }
        else if (uu < 96) { const int x = uu - 48; const int d3 = x / 3; tq = 32 + d3; ci = x - 3 * d3; }
        else              { const int x = uu - 96; tq = 48 + (x >> 2); ci = x & 3; }
    } else { tq = 63 - (bid >> 3); ci = 0; }
    const int q0   = tq << 5;
    const int nvis = q0 + 32;                   // block-causal visible keys
    const int ntt  = (tq + 2) >> 1;             // total 64-key tiles
    const int t0   = SPLIT ? (ci << 3) : 0;
    const int t1   = SPLIT ? min(t0 + 8, ntt) : ntt;
    const int nch  = SPLIT ? ((tq >> 4) + 1) : 1;

    const int tid = threadIdx.x;
    const int wv  = tid >> 6;
    const int ln  = tid & 63;
    const int lq  = ln & 31;
    const int hi  = ln >> 5;
    const int swz = (ln & 7) << 4;
    const int h   = (kh << 2) + wv;

    const float QS = 0.088388347648318447f * 1.4426950408889634f; // SCALE*log2(e)
    short8 qf[8];
    {
        const float* qp = Qg + (size_t)(q0 + lq) * 4096 + h * 128 + hi * 8;
        #pragma unroll
        for (int ds = 0; ds < 8; ++ds){
            const float4 a = *reinterpret_cast<const float4*>(qp + ds * 16);
            const float4 b = *reinterpret_cast<const float4*>(qp + ds * 16 + 4);
            qf[ds] = __builtin_bit_cast(short8,
                make_uint4(pk2(a.x * QS, a.y * QS), pk2(a.z * QS, a.w * QS),
                           pk2(b.x * QS, b.y * QS), pk2(b.z * QS, b.w * QS)));
        }
    }

    f32x16 oa[4];
    #pragma unroll
    for (int i = 0; i < 4; ++i)
        #pragma unroll
        for (int j = 0; j < 16; ++j) oa[i][j] = 0.f;
    float mR = -1e30f, lR = 0.f;

    const int sr = tid >> 2;
    const int sc = (tid & 3) << 5;

    for (int t = t0; t < t1; ++t){
        const int kv0 = t << 6;
        const bool full = (kv0 + 64) <= nvis;

        __syncthreads();
        { // stage K -> kl (bf16, swizzled)
            const float* kp = Kg + (size_t)(kv0 + sr) * 1024 + (kh << 7) + sc;
            #pragma unroll
            for (int w = 0; w < 4; ++w){
                const float4 a = *reinterpret_cast<const float4*>(kp + w * 8);
                const float4 b = *reinterpret_cast<const float4*>(kp + w * 8 + 4);
                const uint4 pkd = make_uint4(pk2(a.x,a.y), pk2(a.z,a.w),
                                             pk2(b.x,b.y), pk2(b.z,b.w));
                const int byte = sr * 256 + (((sc << 1) + (w << 4)) ^ ((sr & 7) << 4));
                *reinterpret_cast<uint4*>(&kl[byte]) = pkd;
            }
            // stage V^T -> vl (bf16, swizzled): vl[d][k] = V[k][d]
            const float* vp = Vg + (size_t)(kv0 + sr) * 1024 + (kh << 7) + sc;
            #pragma unroll
            for (int w = 0; w < 8; ++w){
                const float4 a = *reinterpret_cast<const float4*>(vp + w * 4);
                const float vv[4] = {a.x, a.y, a.z, a.w};
                #pragma unroll
                for (int e = 0; e < 4; ++e){
                    const int row = sc + (w << 2) + e;
                    const int byte = (row << 7) + ((sr << 1) ^ ((row & 7) << 4));
                    *reinterpret_cast<u16*>(&vl[byte]) = f2b(vv[e]);
                }
            }
        }
        __syncthreads();

        // QK^T (swapped)
        f32x16 s0, s1;
        #pragma unroll
        for (int i = 0; i < 16; ++i){ s0[i] = 0.f; s1[i] = 0.f; }
        #pragma unroll
        for (int ds = 0; ds < 8; ++ds){
            const short8 a0 = *reinterpret_cast<const short8*>(
                &kl[lq * 256 + (((ds << 5) + (hi << 4)) ^ swz)]);
            s0 = __builtin_amdgcn_mfma_f32_32x32x16_bf16(a0, qf[ds], s0, 0, 0, 0);
        }
        if (full){
            #pragma unroll
            for (int ds = 0; ds < 8; ++ds){
                const short8 a1 = *reinterpret_cast<const short8*>(
                    &kl[(32 + lq) * 256 + (((ds << 5) + (hi << 4)) ^ swz)]);
                s1 = __builtin_amdgcn_mfma_f32_32x32x16_bf16(a1, qf[ds], s1, 0, 0, 0);
            }
        }

        // online softmax (lane-local per q=lq)
        float p0[16], p1[16];
        float mx = -1e30f;
        #pragma unroll
        for (int r = 0; r < 16; ++r){ p0[r] = s0[r]; mx = fmaxf(mx, s0[r]); }
        if (full){
            #pragma unroll
            for (int r = 0; r < 16; ++r){ p1[r] = s1[r]; mx = fmaxf(mx, s1[r]); }
        }
        mx = fmaxf(mx, __shfl_xor(mx, 32, 64));
        const float mn = fmaxf(mR, mx);
        const float cf = __builtin_exp2f(mR - mn);
        mR = mn;
        float ps = 0.f;
        #pragma unroll
        for (int r = 0; r < 16; ++r){ p0[r] = __builtin_exp2f(p0[r] - mn); ps += p0[r]; }
        if (full){
            #pragma unroll
            for (int r = 0; r < 16; ++r){ p1[r] = __builtin_exp2f(p1[r] - mn); ps += p1[r]; }
        }
        ps += __shfl_xor(ps, 32, 64);
        lR = lR * cf + ps;
        #pragma unroll
        for (int i = 0; i < 4; ++i)
            #pragma unroll
            for (int j = 0; j < 16; ++j) oa[i][j] *= cf;

        // P^T -> bf16 words + partner exchange
        u32 pw0[8], px0[8], pw1[8], px1[8];
        #pragma unroll
        for (int rr = 0; rr < 8; ++rr){
            pw0[rr] = pk2(p0[2*rr], p0[2*rr+1]);
            px0[rr] = (u32)__shfl_xor((int)pw0[rr], 32, 64);
        }
        if (full){
            #pragma unroll
            for (int rr = 0; rr < 8; ++rr){
                pw1[rr] = pk2(p1[2*rr], p1[2*rr+1]);
                px1[rr] = (u32)__shfl_xor((int)pw1[rr], 32, 64);
            }
        }

        // build PV B-fragments
        short8 pf[4];
        #pragma unroll
        for (int ks = 0; ks < 4; ++ks){
            if (ks < 2 || full){
                const u32* pwt = (ks >> 1) ? pw1 : pw0;
                const u32* pxt = (ks >> 1) ? px1 : px0;
                u32 wb[4];
                #pragma unroll
                for (int w = 0; w < 4; ++w){
                    const int b = (w & 1) + ((ks & 1) << 2);
                    const u32 own = hi ? pwt[b + 2] : pwt[b];
                    const u32 oth = hi ? pxt[b + 2] : pxt[b];
                    wb[w] = (hi == (w >> 1)) ? own : oth;
                }
                pf[ks] = __builtin_bit_cast(short8, make_uint4(wb[0], wb[1], wb[2], wb[3]));
            }
        }

        // PV (swapped): O^T[d][q] += V^T[d][k] * P^T[k][q]
        #pragma unroll
        for (int dt = 0; dt < 4; ++dt){
            #pragma unroll
            for (int ks = 0; ks < 4; ++ks){
                if (ks < 2 || full){
                    const short8 vf = *reinterpret_cast<const short8*>(
                        &vl[((dt << 5) + lq) * 128 + (((ks << 5) + (hi << 4)) ^ swz)]);
                    oa[dt] = __builtin_amdgcn_mfma_f32_32x32x16_bf16(vf, pf[ks], oa[dt], 0, 0, 0);
                }
            }
        }
    }

    if (!SPLIT || nch == 1){
        // direct epilogue: O = O^T / l, f32
        const float rl = 1.f / lR;
        float* op = Og + (size_t)(q0 + lq) * 4096 + (h << 7) + (hi << 2);
        #pragma unroll
        for (int dt = 0; dt < 4; ++dt){
            #pragma unroll
            for (int g2 = 0; g2 < 4; ++g2){
                float4 w4;
                w4.x = oa[dt][4*g2 + 0] * rl;
                w4.y = oa[dt][4*g2 + 1] * rl;
                w4.z = oa[dt][4*g2 + 2] * rl;
                w4.w = oa[dt][4*g2 + 3] * rl;
                *reinterpret_cast<float4*>(op + (dt << 5) + (g2 << 3)) = w4;
            }
        }
    } else {
        // partial epilogue: unnormalized bf16 O^T + (m,l) into workspace
        const int pu = ((kh * 144 + (uu - 16)) << 2) + wv;
        char* base = Wg + (size_t)pu * PART_STRIDE;
        #pragma unroll
        for (int i = 0; i < 8; ++i){
            const int e0 = i * 8;
            uint4 w4;
            w4.x = pk2(oa[(e0+0)>>4][(e0+0)&15], oa[(e0+1)>>4][(e0+1)&15]);
            w4.y = pk2(oa[(e0+2)>>4][(e0+2)&15], oa[(e0+3)>>4][(e0+3)&15]);
            w4.z = pk2(oa[(e0+4)>>4][(e0+4)&15], oa[(e0+5)>>4][(e0+5)&15]);
            w4.w = pk2(oa[(e0+6)>>4][(e0+6)&15], oa[(e0+7)>>4][(e0+7)&15]);
            *reinterpret_cast<uint4*>(base + ln * 128 + i * 16) = w4;
        }
        if (hi == 0){
            *reinterpret_cast<float*>(base + 8192 + lq * 4) = mR;
            *reinterpret_cast<float*>(base + 8320 + lq * 4) = lR;
        }
    }
}

// Merge: one wave per (q-head, q-tile>=16); exp2-weighted partial combine.
__global__ __launch_bounds__(64, 4)
void dllm_merge(float* __restrict__ Og, const char* __restrict__ Wg)
{
    __shared__ float lds2[32][132];
    const int b  = blockIdx.x;            // [0, 1536)
    const int h  = b & 31;
    const int tq = 16 + (b >> 5);
    const int kh = h >> 2, wv = h & 3;
    const int nch = (tq >> 4) + 1;        // 2..4
    int ub;
    if (tq < 32)      ub = 16 + ((tq - 16) << 1);
    else if (tq < 48) ub = 48 + (tq - 32) * 3;
    else              ub = 96 + ((tq - 48) << 2);

    const int ln = threadIdx.x;
    const int lq = ln & 31, hi = ln >> 5;

    const char* bases[4];
    float mv[4], lv[4];
    float M = -1e30f;
    for (int c = 0; c < 4; ++c){
        if (c < nch){
            bases[c] = Wg + (size_t)(((kh * 144 + (ub - 16 + c)) << 2) + wv) * PART_STRIDE;
            mv[c] = *reinterpret_cast<const float*>(bases[c] + 8192 + lq * 4);
            lv[c] = *reinterpret_cast<const float*>(bases[c] + 8320 + lq * 4);
            M = fmaxf(M, mv[c]);
        }
    }
    float wsum = 0.f;
    float acc[64];
    #pragma unroll
    for (int e = 0; e < 64; ++e) acc[e] = 0.f;
    for (int c = 0; c < 4; ++c){
        if (c < nch){
            const float w = __builtin_exp2f(mv[c] - M);
            wsum += lv[c] * w;
            const uint4* pp = reinterpret_cast<const uint4*>(bases[c] + ln * 128);
            #pragma unroll
            for (int i = 0; i < 8; ++i){
                const uint4 w4 = pp[i];
                const u32 ww[4] = {w4.x, w4.y, w4.z, w4.w};
                #pragma unroll
                for (int k = 0; k < 4; ++k){
                    acc[i*8 + k*2 + 0] += b2f((u16)(ww[k] & 0xffffu)) * w;
                    acc[i*8 + k*2 + 1] += b2f((u16)(ww[k] >> 16)) * w;
                }
            }
        }
    }
    const float rl = 1.f / wsum;
    #pragma unroll
    for (int e = 0; e < 64; ++e){
        const int dt = e >> 4, j = e & 15;
        lds2[lq][dt*32 + (j & 3) + ((j >> 2) << 3) + (hi << 2)] = acc[e] * rl;
    }
    __syncthreads();
    const int q0 = tq << 5;
    #pragma unroll
    for (int it = 0; it < 16; ++it){
        const int idx = it * 64 + ln;
        const int row = idx >> 5;
        const int c4  = idx & 31;
        const float4 v = *reinterpret_cast<const float4*>(&lds2[row][c4 * 4]);
        *reinterpret_cast<float4*>(Og + (size_t)(q0 + row) * 4096 + h * 128 + c4 * 4) = v;
    }
}

extern "C" void kernel_launch(void* const* d_in, const int* in_sizes, int n_in,
                              void* d_out, int out_size, void* d_ws, size_t ws_size,
                              hipStream_t stream) {
    const float* Q = (const float*)d_in[0];
    const float* K = (const float*)d_in[1];
    const float* V = (const float*)d_in[2];
    float* O = (float*)d_out;
    const size_t need = (size_t)4608 * PART_STRIDE;   // 38.9 MB of partials
    if (ws_size >= need){
        dllm_attn<true><<<dim3(1280), dim3(256), 0, stream>>>(Q, K, V, O, (char*)d_ws);
        dllm_merge<<<dim3(1536), dim3(64), 0, stream>>>(O, (const char*)d_ws);
    } else {
        // fallback: monolithic (R3-verified) path
        dllm_attn<false><<<dim3(512), dim3(256), 0, stream>>>(Q, K, V, O, (char*)d_ws);
    }
}

// Round 5
// 229.698 us; speedup vs baseline: 2.0131x; 2.0131x over previous
//
#include <hip/hip_runtime.h>
#include <hip/hip_bf16.h>

typedef __attribute__((ext_vector_type(8)))  short short8;
typedef __attribute__((ext_vector_type(16))) float f32x16;
typedef unsigned short u16;
typedef unsigned int   u32;

__device__ __forceinline__ u16 f2b(float f){
    __hip_bfloat16 h = __float2bfloat16(f);
    u16 u; __builtin_memcpy(&u, &h, 2); return u;
}
__device__ __forceinline__ u32 pk2(float lo, float hi){
    return (u32)f2b(lo) | ((u32)f2b(hi) << 16);
}
__device__ __forceinline__ float b2f(u16 u){
    u32 w = ((u32)u) << 16; float f; __builtin_memcpy(&f, &w, 4); return f;
}

#define PART_STRIDE 8448  // 64*128B bf16 O^T + 32 f32 m + 32 f32 l (16B-aligned)

// S=2048, H=32, HKV=8, G=4, D=128, DIFF_BS=32
// Split-KV flash-decode: block = (kv-head, q-tile, kv-chunk of 512 keys).
// 4 waves = 4 GQA query heads. Swapped QK^T / PV (R3-verified math).
// NOTE R4 post-mortem: __launch_bounds__(256,4) capped VGPR at 64 -> spills
// (FETCH 27->457MB). Keep (256,2): 116 VGPR, no spill; HW still fits 4
// blocks/CU from actual usage.
template<bool SPLIT>
__global__ __launch_bounds__(256, 2)
void dllm_attn(const float* __restrict__ Qg, const float* __restrict__ Kg,
               const float* __restrict__ Vg, float* __restrict__ Og,
               char* __restrict__ Wg)
{
    __shared__ alignas(16) char kl[64 * 256];   // K tile bf16 [64][128], XOR-swizzled
    __shared__ alignas(16) char vl[128 * 128];  // V^T tile bf16 [128][64], XOR-swizzled

    const int bid = blockIdx.x;
    const int kh  = bid & 7;
    int tq, ci, uu = 0;
    if (SPLIT){
        uu = 159 - (bid >> 3);                  // big tiles first
        if (uu < 16)      { tq = uu; ci = 0; }
        else if (uu < 48) { const int x = uu - 16; tq = 16 + (x >> 1); ci = x & 1; }
        else if (uu < 96) { const int x = uu - 48; const int d3 = x / 3; tq = 32 + d3; ci = x - 3 * d3; }
        else              { const int x = uu - 96; tq = 48 + (x >> 2); ci = x & 3; }
    } else { tq = 63 - (bid >> 3); ci = 0; }
    const int q0   = tq << 5;
    const int nvis = q0 + 32;                   // block-causal visible keys
    const int ntt  = (tq + 2) >> 1;             // total 64-key tiles
    const int t0   = SPLIT ? (ci << 3) : 0;
    const int t1   = SPLIT ? min(t0 + 8, ntt) : ntt;
    const int nch  = SPLIT ? ((tq >> 4) + 1) : 1;

    const int tid = threadIdx.x;
    const int wv  = tid >> 6;
    const int ln  = tid & 63;
    const int lq  = ln & 31;
    const int hi  = ln >> 5;
    const int swz = (ln & 7) << 4;
    const int h   = (kh << 2) + wv;

    const float QS = 0.088388347648318447f * 1.4426950408889634f; // SCALE*log2(e)
    short8 qf[8];
    {
        const float* qp = Qg + (size_t)(q0 + lq) * 4096 + h * 128 + hi * 8;
        #pragma unroll
        for (int ds = 0; ds < 8; ++ds){
            const float4 a = *reinterpret_cast<const float4*>(qp + ds * 16);
            const float4 b = *reinterpret_cast<const float4*>(qp + ds * 16 + 4);
            qf[ds] = __builtin_bit_cast(short8,
                make_uint4(pk2(a.x * QS, a.y * QS), pk2(a.z * QS, a.w * QS),
                           pk2(b.x * QS, b.y * QS), pk2(b.z * QS, b.w * QS)));
        }
    }

    f32x16 oa[4];
    #pragma unroll
    for (int i = 0; i < 4; ++i)
        #pragma unroll
        for (int j = 0; j < 16; ++j) oa[i][j] = 0.f;
    float mR = -1e30f, lR = 0.f;

    const int sr = tid >> 2;
    const int sc = (tid & 3) << 5;

    for (int t = t0; t < t1; ++t){
        const int kv0 = t << 6;
        const bool full = (kv0 + 64) <= nvis;

        __syncthreads();
        { // stage K -> kl (bf16, swizzled)
            const float* kp = Kg + (size_t)(kv0 + sr) * 1024 + (kh << 7) + sc;
            #pragma unroll
            for (int w = 0; w < 4; ++w){
                const float4 a = *reinterpret_cast<const float4*>(kp + w * 8);
                const float4 b = *reinterpret_cast<const float4*>(kp + w * 8 + 4);
                const uint4 pkd = make_uint4(pk2(a.x,a.y), pk2(a.z,a.w),
                                             pk2(b.x,b.y), pk2(b.z,b.w));
                const int byte = sr * 256 + (((sc << 1) + (w << 4)) ^ ((sr & 7) << 4));
                *reinterpret_cast<uint4*>(&kl[byte]) = pkd;
            }
            // stage V^T -> vl (bf16, swizzled): vl[d][k] = V[k][d]
            const float* vp = Vg + (size_t)(kv0 + sr) * 1024 + (kh << 7) + sc;
            #pragma unroll
            for (int w = 0; w < 8; ++w){
                const float4 a = *reinterpret_cast<const float4*>(vp + w * 4);
                const float vv[4] = {a.x, a.y, a.z, a.w};
                #pragma unroll
                for (int e = 0; e < 4; ++e){
                    const int row = sc + (w << 2) + e;
                    const int byte = (row << 7) + ((sr << 1) ^ ((row & 7) << 4));
                    *reinterpret_cast<u16*>(&vl[byte]) = f2b(vv[e]);
                }
            }
        }
        __syncthreads();

        // QK^T (swapped)
        f32x16 s0, s1;
        #pragma unroll
        for (int i = 0; i < 16; ++i){ s0[i] = 0.f; s1[i] = 0.f; }
        #pragma unroll
        for (int ds = 0; ds < 8; ++ds){
            const short8 a0 = *reinterpret_cast<const short8*>(
                &kl[lq * 256 + (((ds << 5) + (hi << 4)) ^ swz)]);
            s0 = __builtin_amdgcn_mfma_f32_32x32x16_bf16(a0, qf[ds], s0, 0, 0, 0);
        }
        if (full){
            #pragma unroll
            for (int ds = 0; ds < 8; ++ds){
                const short8 a1 = *reinterpret_cast<const short8*>(
                    &kl[(32 + lq) * 256 + (((ds << 5) + (hi << 4)) ^ swz)]);
                s1 = __builtin_amdgcn_mfma_f32_32x32x16_bf16(a1, qf[ds], s1, 0, 0, 0);
            }
        }

        // online softmax (lane-local per q=lq)
        float p0[16], p1[16];
        float mx = -1e30f;
        #pragma unroll
        for (int r = 0; r < 16; ++r){ p0[r] = s0[r]; mx = fmaxf(mx, s0[r]); }
        if (full){
            #pragma unroll
            for (int r = 0; r < 16; ++r){ p1[r] = s1[r]; mx = fmaxf(mx, s1[r]); }
        }
        mx = fmaxf(mx, __shfl_xor(mx, 32, 64));
        const float mn = fmaxf(mR, mx);
        const float cf = __builtin_exp2f(mR - mn);
        mR = mn;
        float ps = 0.f;
        #pragma unroll
        for (int r = 0; r < 16; ++r){ p0[r] = __builtin_exp2f(p0[r] - mn); ps += p0[r]; }
        if (full){
            #pragma unroll
            for (int r = 0; r < 16; ++r){ p1[r] = __builtin_exp2f(p1[r] - mn); ps += p1[r]; }
        }
        ps += __shfl_xor(ps, 32, 64);
        lR = lR * cf + ps;
        #pragma unroll
        for (int i = 0; i < 4; ++i)
            #pragma unroll
            for (int j = 0; j < 16; ++j) oa[i][j] *= cf;

        // P^T -> bf16 words + partner exchange
        u32 pw0[8], px0[8], pw1[8], px1[8];
        #pragma unroll
        for (int rr = 0; rr < 8; ++rr){
            pw0[rr] = pk2(p0[2*rr], p0[2*rr+1]);
            px0[rr] = (u32)__shfl_xor((int)pw0[rr], 32, 64);
        }
        if (full){
            #pragma unroll
            for (int rr = 0; rr < 8; ++rr){
                pw1[rr] = pk2(p1[2*rr], p1[2*rr+1]);
                px1[rr] = (u32)__shfl_xor((int)pw1[rr], 32, 64);
            }
        }

        // build PV B-fragments
        short8 pf[4];
        #pragma unroll
        for (int ks = 0; ks < 4; ++ks){
            if (ks < 2 || full){
                const u32* pwt = (ks >> 1) ? pw1 : pw0;
                const u32* pxt = (ks >> 1) ? px1 : px0;
                u32 wb[4];
                #pragma unroll
                for (int w = 0; w < 4; ++w){
                    const int b = (w & 1) + ((ks & 1) << 2);
                    const u32 own = hi ? pwt[b + 2] : pwt[b];
                    const u32 oth = hi ? pxt[b + 2] : pxt[b];
                    wb[w] = (hi == (w >> 1)) ? own : oth;
                }
                pf[ks] = __builtin_bit_cast(short8, make_uint4(wb[0], wb[1], wb[2], wb[3]));
            }
        }

        // PV (swapped): O^T[d][q] += V^T[d][k] * P^T[k][q]
        #pragma unroll
        for (int dt = 0; dt < 4; ++dt){
            #pragma unroll
            for (int ks = 0; ks < 4; ++ks){
                if (ks < 2 || full){
                    const short8 vf = *reinterpret_cast<const short8*>(
                        &vl[((dt << 5) + lq) * 128 + (((ks << 5) + (hi << 4)) ^ swz)]);
                    oa[dt] = __builtin_amdgcn_mfma_f32_32x32x16_bf16(vf, pf[ks], oa[dt], 0, 0, 0);
                }
            }
        }
    }

    if (!SPLIT || nch == 1){
        // direct epilogue: O = O^T / l, f32
        const float rl = 1.f / lR;
        float* op = Og + (size_t)(q0 + lq) * 4096 + (h << 7) + (hi << 2);
        #pragma unroll
        for (int dt = 0; dt < 4; ++dt){
            #pragma unroll
            for (int g2 = 0; g2 < 4; ++g2){
                float4 w4;
                w4.x = oa[dt][4*g2 + 0] * rl;
                w4.y = oa[dt][4*g2 + 1] * rl;
                w4.z = oa[dt][4*g2 + 2] * rl;
                w4.w = oa[dt][4*g2 + 3] * rl;
                *reinterpret_cast<float4*>(op + (dt << 5) + (g2 << 3)) = w4;
            }
        }
    } else {
        // partial epilogue: unnormalized bf16 O^T + (m,l) into workspace
        const int pu = ((kh * 144 + (uu - 16)) << 2) + wv;
        char* base = Wg + (size_t)pu * PART_STRIDE;
        #pragma unroll
        for (int i = 0; i < 8; ++i){
            const int e0 = i * 8;
            uint4 w4;
            w4.x = pk2(oa[(e0+0)>>4][(e0+0)&15], oa[(e0+1)>>4][(e0+1)&15]);
            w4.y = pk2(oa[(e0+2)>>4][(e0+2)&15], oa[(e0+3)>>4][(e0+3)&15]);
            w4.z = pk2(oa[(e0+4)>>4][(e0+4)&15], oa[(e0+5)>>4][(e0+5)&15]);
            w4.w = pk2(oa[(e0+6)>>4][(e0+6)&15], oa[(e0+7)>>4][(e0+7)&15]);
            *reinterpret_cast<uint4*>(base + ln * 128 + i * 16) = w4;
        }
        if (hi == 0){
            *reinterpret_cast<float*>(base + 8192 + lq * 4) = mR;
            *reinterpret_cast<float*>(base + 8320 + lq * 4) = lR;
        }
    }
}

// Merge: one wave per (q-head, q-tile>=16); exp2-weighted partial combine.
__global__ __launch_bounds__(64, 4)
void dllm_merge(float* __restrict__ Og, const char* __restrict__ Wg)
{
    __shared__ float lds2[32][132];
    const int b  = blockIdx.x;            // [0, 1536)
    const int h  = b & 31;
    const int tq = 16 + (b >> 5);
    const int kh = h >> 2, wv = h & 3;
    const int nch = (tq >> 4) + 1;        // 2..4
    int ub;
    if (tq < 32)      ub = 16 + ((tq - 16) << 1);
    else if (tq < 48) ub = 48 + (tq - 32) * 3;
    else              ub = 96 + ((tq - 48) << 2);

    const int ln = threadIdx.x;
    const int lq = ln & 31, hi = ln >> 5;

    const char* bases[4];
    float mv[4], lv[4];
    float M = -1e30f;
    for (int c = 0; c < 4; ++c){
        if (c < nch){
            bases[c] = Wg + (size_t)(((kh * 144 + (ub - 16 + c)) << 2) + wv) * PART_STRIDE;
            mv[c] = *reinterpret_cast<const float*>(bases[c] + 8192 + lq * 4);
            lv[c] = *reinterpret_cast<const float*>(bases[c] + 8320 + lq * 4);
            M = fmaxf(M, mv[c]);
        }
    }
    float wsum = 0.f;
    float acc[64];
    #pragma unroll
    for (int e = 0; e < 64; ++e) acc[e] = 0.f;
    for (int c = 0; c < 4; ++c){
        if (c < nch){
            const float w = __builtin_exp2f(mv[c] - M);
            wsum += lv[c] * w;
            const uint4* pp = reinterpret_cast<const uint4*>(bases[c] + ln * 128);
            #pragma unroll
            for (int i = 0; i < 8; ++i){
                const uint4 w4 = pp[i];
                const u32 ww[4] = {w4.x, w4.y, w4.z, w4.w};
                #pragma unroll
                for (int k = 0; k < 4; ++k){
                    acc[i*8 + k*2 + 0] += b2f((u16)(ww[k] & 0xffffu)) * w;
                    acc[i*8 + k*2 + 1] += b2f((u16)(ww[k] >> 16)) * w;
                }
            }
        }
    }
    const float rl = 1.f / wsum;
    #pragma unroll
    for (int e = 0; e < 64; ++e){
        const int dt = e >> 4, j = e & 15;
        lds2[lq][dt*32 + (j & 3) + ((j >> 2) << 3) + (hi << 2)] = acc[e] * rl;
    }
    __syncthreads();
    const int q0 = tq << 5;
    #pragma unroll
    for (int it = 0; it < 16; ++it){
        const int idx = it * 64 + ln;
        const int row = idx >> 5;
        const int c4  = idx & 31;
        const float4 v = *reinterpret_cast<const float4*>(&lds2[row][c4 * 4]);
        *reinterpret_cast<float4*>(Og + (size_t)(q0 + row) * 4096 + h * 128 + c4 * 4) = v;
    }
}

extern "C" void kernel_launch(void* const* d_in, const int* in_sizes, int n_in,
                              void* d_out, int out_size, void* d_ws, size_t ws_size,
                              hipStream_t stream) {
    const float* Q = (const float*)d_in[0];
    const float* K = (const float*)d_in[1];
    const float* V = (const float*)d_in[2];
    float* O = (float*)d_out;
    const size_t need = (size_t)4608 * PART_STRIDE;   // 38.9 MB of partials
    if (ws_size >= need){
        dllm_attn<true><<<dim3(1280), dim3(256), 0, stream>>>(Q, K, V, O, (char*)d_ws);
        dllm_merge<<<dim3(1536), dim3(64), 0, stream>>>(O, (const char*)d_ws);
    } else {
        // fallback: monolithic (R3-verified) path
        dllm_attn<false><<<dim3(512), dim3(256), 0, stream>>>(Q, K, V, O, (char*)d_ws);
    }
}

// Round 6
// 228.153 us; speedup vs baseline: 2.0267x; 1.0068x over previous
//
#include <hip/hip_runtime.h>
#include <hip/hip_bf16.h>

typedef __attribute__((ext_vector_type(8)))  short short8;
typedef __attribute__((ext_vector_type(16))) float f32x16;
typedef unsigned short u16;
typedef unsigned int   u32;

__device__ __forceinline__ u16 f2b(float f){
    __hip_bfloat16 h = __float2bfloat16(f);
    u16 u; __builtin_memcpy(&u, &h, 2); return u;
}
__device__ __forceinline__ u32 pk2(float lo, float hi){
    return (u32)f2b(lo) | ((u32)f2b(hi) << 16);
}
__device__ __forceinline__ float b2f(u16 u){
    u32 w = ((u32)u) << 16; float f; __builtin_memcpy(&f, &w, 4); return f;
}

#define PART_STRIDE 8448  // 64*128B bf16 O^T + 32 f32 m + 32 f32 l (16B-aligned)

// S=2048, H=32, HKV=8, G=4, D=128, DIFF_BS=32
// Split-KV flash-decode: block = (kv-head, q-tile, kv-chunk of 512 keys).
// 4 waves = 4 GQA query heads. Swapped QK^T / PV (R3-verified math).
// R4 post-mortem: __launch_bounds__(256,4) capped VGPR at 64 -> spills. Keep (256,2).
template<bool SPLIT>
__global__ __launch_bounds__(256, 2)
void dllm_attn(const float* __restrict__ Qg, const float* __restrict__ Kg,
               const float* __restrict__ Vg, float* __restrict__ Og,
               char* __restrict__ Wg)
{
    __shared__ alignas(16) char kl[64 * 256];   // K tile bf16 [64][128], XOR-swizzled
    __shared__ alignas(16) char vl[128 * 128];  // V^T tile bf16 [128][64], XOR-swizzled

    const int bid = blockIdx.x;
    const int kh  = bid & 7;
    int tq, ci, uu = 0;
    if (SPLIT){
        uu = 159 - (bid >> 3);                  // big tiles first
        if (uu < 16)      { tq = uu; ci = 0; }
        else if (uu < 48) { const int x = uu - 16; tq = 16 + (x >> 1); ci = x & 1; }
        else if (uu < 96) { const int x = uu - 48; const int d3 = x / 3; tq = 32 + d3; ci = x - 3 * d3; }
        else              { const int x = uu - 96; tq = 48 + (x >> 2); ci = x & 3; }
    } else { tq = 63 - (bid >> 3); ci = 0; }
    const int q0   = tq << 5;
    const int nvis = q0 + 32;                   // block-causal visible keys
    const int ntt  = (tq + 2) >> 1;             // total 64-key tiles
    const int t0   = SPLIT ? (ci << 3) : 0;
    const int t1   = SPLIT ? min(t0 + 8, ntt) : ntt;
    const int nch  = SPLIT ? ((tq >> 4) + 1) : 1;

    const int tid = threadIdx.x;
    const int wv  = tid >> 6;
    const int ln  = tid & 63;
    const int lq  = ln & 31;
    const int hi  = ln >> 5;
    const int swz = (ln & 7) << 4;
    const int h   = (kh << 2) + wv;

    const float QS = 0.088388347648318447f * 1.4426950408889634f; // SCALE*log2(e)
    short8 qf[8];
    {
        const float* qp = Qg + (size_t)(q0 + lq) * 4096 + h * 128 + hi * 8;
        #pragma unroll
        for (int ds = 0; ds < 8; ++ds){
            const float4 a = *reinterpret_cast<const float4*>(qp + ds * 16);
            const float4 b = *reinterpret_cast<const float4*>(qp + ds * 16 + 4);
            qf[ds] = __builtin_bit_cast(short8,
                make_uint4(pk2(a.x * QS, a.y * QS), pk2(a.z * QS, a.w * QS),
                           pk2(b.x * QS, b.y * QS), pk2(b.z * QS, b.w * QS)));
        }
    }

    f32x16 oa[4];
    #pragma unroll
    for (int i = 0; i < 4; ++i)
        #pragma unroll
        for (int j = 0; j < 16; ++j) oa[i][j] = 0.f;
    float mR = -1e30f, lR = 0.f;

    const int sr = tid >> 2;
    const int sc = (tid & 3) << 5;

    for (int t = t0; t < t1; ++t){
        const int kv0 = t << 6;
        const bool full = (kv0 + 64) <= nvis;

        __syncthreads();
        { // stage K -> kl (bf16, swizzled)
            const float* kp = Kg + (size_t)(kv0 + sr) * 1024 + (kh << 7) + sc;
            #pragma unroll
            for (int w = 0; w < 4; ++w){
                const float4 a = *reinterpret_cast<const float4*>(kp + w * 8);
                const float4 b = *reinterpret_cast<const float4*>(kp + w * 8 + 4);
                const uint4 pkd = make_uint4(pk2(a.x,a.y), pk2(a.z,a.w),
                                             pk2(b.x,b.y), pk2(b.z,b.w));
                const int byte = sr * 256 + (((sc << 1) + (w << 4)) ^ ((sr & 7) << 4));
                *reinterpret_cast<uint4*>(&kl[byte]) = pkd;
            }
            // stage V^T -> vl (bf16, swizzled): vl[d][k] = V[k][d]
            const float* vp = Vg + (size_t)(kv0 + sr) * 1024 + (kh << 7) + sc;
            #pragma unroll
            for (int w = 0; w < 8; ++w){
                const float4 a = *reinterpret_cast<const float4*>(vp + w * 4);
                const float vv[4] = {a.x, a.y, a.z, a.w};
                #pragma unroll
                for (int e = 0; e < 4; ++e){
                    const int row = sc + (w << 2) + e;
                    const int byte = (row << 7) + ((sr << 1) ^ ((row & 7) << 4));
                    *reinterpret_cast<u16*>(&vl[byte]) = f2b(vv[e]);
                }
            }
        }
        __syncthreads();

        // QK^T (swapped)
        f32x16 s0, s1;
        #pragma unroll
        for (int i = 0; i < 16; ++i){ s0[i] = 0.f; s1[i] = 0.f; }
        #pragma unroll
        for (int ds = 0; ds < 8; ++ds){
            const short8 a0 = *reinterpret_cast<const short8*>(
                &kl[lq * 256 + (((ds << 5) + (hi << 4)) ^ swz)]);
            s0 = __builtin_amdgcn_mfma_f32_32x32x16_bf16(a0, qf[ds], s0, 0, 0, 0);
        }
        if (full){
            #pragma unroll
            for (int ds = 0; ds < 8; ++ds){
                const short8 a1 = *reinterpret_cast<const short8*>(
                    &kl[(32 + lq) * 256 + (((ds << 5) + (hi << 4)) ^ swz)]);
                s1 = __builtin_amdgcn_mfma_f32_32x32x16_bf16(a1, qf[ds], s1, 0, 0, 0);
            }
        }

        // online softmax (lane-local per q=lq)
        float p0[16], p1[16];
        float mx = -1e30f;
        #pragma unroll
        for (int r = 0; r < 16; ++r){ p0[r] = s0[r]; mx = fmaxf(mx, s0[r]); }
        if (full){
            #pragma unroll
            for (int r = 0; r < 16; ++r){ p1[r] = s1[r]; mx = fmaxf(mx, s1[r]); }
        }
        mx = fmaxf(mx, __shfl_xor(mx, 32, 64));
        const float mn = fmaxf(mR, mx);
        const float cf = __builtin_exp2f(mR - mn);
        mR = mn;
        float ps = 0.f;
        #pragma unroll
        for (int r = 0; r < 16; ++r){ p0[r] = __builtin_exp2f(p0[r] - mn); ps += p0[r]; }
        if (full){
            #pragma unroll
            for (int r = 0; r < 16; ++r){ p1[r] = __builtin_exp2f(p1[r] - mn); ps += p1[r]; }
        }
        ps += __shfl_xor(ps, 32, 64);
        lR = lR * cf + ps;
        #pragma unroll
        for (int i = 0; i < 4; ++i)
            #pragma unroll
            for (int j = 0; j < 16; ++j) oa[i][j] *= cf;

        // P^T -> bf16 words + partner exchange
        u32 pw0[8], px0[8], pw1[8], px1[8];
        #pragma unroll
        for (int rr = 0; rr < 8; ++rr){
            pw0[rr] = pk2(p0[2*rr], p0[2*rr+1]);
            px0[rr] = (u32)__shfl_xor((int)pw0[rr], 32, 64);
        }
        if (full){
            #pragma unroll
            for (int rr = 0; rr < 8; ++rr){
                pw1[rr] = pk2(p1[2*rr], p1[2*rr+1]);
                px1[rr] = (u32)__shfl_xor((int)pw1[rr], 32, 64);
            }
        }

        // build PV B-fragments
        short8 pf[4];
        #pragma unroll
        for (int ks = 0; ks < 4; ++ks){
            if (ks < 2 || full){
                const u32* pwt = (ks >> 1) ? pw1 : pw0;
                const u32* pxt = (ks >> 1) ? px1 : px0;
                u32 wb[4];
                #pragma unroll
                for (int w = 0; w < 4; ++w){
                    const int b = (w & 1) + ((ks & 1) << 2);
                    const u32 own = hi ? pwt[b + 2] : pwt[b];
                    const u32 oth = hi ? pxt[b + 2] : pxt[b];
                    wb[w] = (hi == (w >> 1)) ? own : oth;
                }
                pf[ks] = __builtin_bit_cast(short8, make_uint4(wb[0], wb[1], wb[2], wb[3]));
            }
        }

        // PV (swapped): O^T[d][q] += V^T[d][k] * P^T[k][q]
        #pragma unroll
        for (int dt = 0; dt < 4; ++dt){
            #pragma unroll
            for (int ks = 0; ks < 4; ++ks){
                if (ks < 2 || full){
                    const short8 vf = *reinterpret_cast<const short8*>(
                        &vl[((dt << 5) + lq) * 128 + (((ks << 5) + (hi << 4)) ^ swz)]);
                    oa[dt] = __builtin_amdgcn_mfma_f32_32x32x16_bf16(vf, pf[ks], oa[dt], 0, 0, 0);
                }
            }
        }
    }

    if (!SPLIT || nch == 1){
        // direct epilogue: O = O^T / l, f32
        const float rl = 1.f / lR;
        float* op = Og + (size_t)(q0 + lq) * 4096 + (h << 7) + (hi << 2);
        #pragma unroll
        for (int dt = 0; dt < 4; ++dt){
            #pragma unroll
            for (int g2 = 0; g2 < 4; ++g2){
                float4 w4;
                w4.x = oa[dt][4*g2 + 0] * rl;
                w4.y = oa[dt][4*g2 + 1] * rl;
                w4.z = oa[dt][4*g2 + 2] * rl;
                w4.w = oa[dt][4*g2 + 3] * rl;
                *reinterpret_cast<float4*>(op + (dt << 5) + (g2 << 3)) = w4;
            }
        }
    } else {
        // partial epilogue: unnormalized bf16 O^T + (m,l) into workspace
        const int pu = ((kh * 144 + (uu - 16)) << 2) + wv;
        char* base = Wg + (size_t)pu * PART_STRIDE;
        #pragma unroll
        for (int i = 0; i < 8; ++i){
            const int e0 = i * 8;
            uint4 w4;
            w4.x = pk2(oa[(e0+0)>>4][(e0+0)&15], oa[(e0+1)>>4][(e0+1)&15]);
            w4.y = pk2(oa[(e0+2)>>4][(e0+2)&15], oa[(e0+3)>>4][(e0+3)&15]);
            w4.z = pk2(oa[(e0+4)>>4][(e0+4)&15], oa[(e0+5)>>4][(e0+5)&15]);
            w4.w = pk2(oa[(e0+6)>>4][(e0+6)&15], oa[(e0+7)>>4][(e0+7)&15]);
            *reinterpret_cast<uint4*>(base + ln * 128 + i * 16) = w4;
        }
        if (hi == 0){
            *reinterpret_cast<float*>(base + 8192 + lq * 4) = mR;
            *reinterpret_cast<float*>(base + 8320 + lq * 4) = lR;
        }
    }
}

// Merge v2: 256 threads/block, one block per (q-head, q-tile>=16).
// Thread (q=tid>>3, s=tid&7) owns 16 consecutive d at d0=16s of row q.
// Partial O^T layout inversion: element e at lane ln, byte ln*128+i*16+k*4
// holds (d, d+1) with d = 16*i + 8*(k>>1) + 2*(k&1) + 4*(ln>>5) -> 16
// consecutive d == two uint4 loads (lane rows q and q+32). All chunk loads
// issued up front (latency overlap); static-indexed unpack; float4 stores.
__global__ __launch_bounds__(256, 2)
void dllm_merge(float* __restrict__ Og, const char* __restrict__ Wg)
{
    const int b  = blockIdx.x;            // [0, 1536)
    const int h  = b & 31;
    const int tq = 16 + (b >> 5);
    const int kh = h >> 2, wv = h & 3;
    const int nch = (tq >> 4) + 1;        // 2..4
    int ub;
    if (tq < 32)      ub = 16 + ((tq - 16) << 1);
    else if (tq < 48) ub = 48 + (tq - 32) * 3;
    else              ub = 96 + ((tq - 48) << 2);

    const int tid = threadIdx.x;
    const int q   = tid >> 3;             // 0..31
    const int s   = tid & 7;              // d0 = 16*s

    const char* bases[4];
    float mv[4], lv[4];
    float M = -1e30f;
    #pragma unroll
    for (int c = 0; c < 4; ++c){
        if (c < nch){
            bases[c] = Wg + (size_t)(((kh * 144 + (ub - 16 + c)) << 2) + wv) * PART_STRIDE;
            mv[c] = *reinterpret_cast<const float*>(bases[c] + 8192 + q * 4);
            lv[c] = *reinterpret_cast<const float*>(bases[c] + 8320 + q * 4);
            M = fmaxf(M, mv[c]);
        }
    }
    uint4 wlo[4], whi[4];
    #pragma unroll
    for (int c = 0; c < 4; ++c){
        if (c < nch){
            wlo[c] = *reinterpret_cast<const uint4*>(bases[c] + q * 128 + s * 16);
            whi[c] = *reinterpret_cast<const uint4*>(bases[c] + (q + 32) * 128 + s * 16);
        }
    }
    float wsum = 0.f;
    float acc[16];
    #pragma unroll
    for (int e = 0; e < 16; ++e) acc[e] = 0.f;
    #pragma unroll
    for (int c = 0; c < 4; ++c){
        if (c < nch){
            const float w = __builtin_exp2f(mv[c] - M);
            wsum += lv[c] * w;
            const u32 wl[4] = {wlo[c].x, wlo[c].y, wlo[c].z, wlo[c].w};
            const u32 wh[4] = {whi[c].x, whi[c].y, whi[c].z, whi[c].w};
            #pragma unroll
            for (int k = 0; k < 4; ++k){
                const int dl = ((k & 1) << 1) + ((k >> 1) << 3);   // 0,2,8,10
                acc[dl + 0] += b2f((u16)(wl[k] & 0xffffu)) * w;
                acc[dl + 1] += b2f((u16)(wl[k] >> 16)) * w;
                acc[dl + 4] += b2f((u16)(wh[k] & 0xffffu)) * w;
                acc[dl + 5] += b2f((u16)(wh[k] >> 16)) * w;
            }
        }
    }
    const float rl = 1.f / wsum;
    float* op = Og + (size_t)((tq << 5) + q) * 4096 + h * 128 + (s << 4);
    #pragma unroll
    for (int g = 0; g < 4; ++g){
        float4 v4;
        v4.x = acc[g*4 + 0] * rl;
        v4.y = acc[g*4 + 1] * rl;
        v4.z = acc[g*4 + 2] * rl;
        v4.w = acc[g*4 + 3] * rl;
        *reinterpret_cast<float4*>(op + (g << 2)) = v4;
    }
}

extern "C" void kernel_launch(void* const* d_in, const int* in_sizes, int n_in,
                              void* d_out, int out_size, void* d_ws, size_t ws_size,
                              hipStream_t stream) {
    const float* Q = (const float*)d_in[0];
    const float* K = (const float*)d_in[1];
    const float* V = (const float*)d_in[2];
    float* O = (float*)d_out;
    const size_t need = (size_t)4608 * PART_STRIDE;   // 38.9 MB of partials
    if (ws_size >= need){
        dllm_attn<true><<<dim3(1280), dim3(256), 0, stream>>>(Q, K, V, O, (char*)d_ws);
        dllm_merge<<<dim3(1536), dim3(256), 0, stream>>>(O, (const char*)d_ws);
    } else {
        // fallback: monolithic (R3-verified) path
        dllm_attn<false><<<dim3(512), dim3(256), 0, stream>>>(Q, K, V, O, (char*)d_ws);
    }
}

// Round 7
// 211.458 us; speedup vs baseline: 2.1867x; 1.0790x over previous
//
#include <hip/hip_runtime.h>
#include <hip/hip_bf16.h>

typedef __attribute__((ext_vector_type(8)))  short short8;
typedef __attribute__((ext_vector_type(16))) float f32x16;
typedef unsigned short u16;
typedef unsigned int   u32;

__device__ __forceinline__ u16 f2b(float f){
    __hip_bfloat16 h = __float2bfloat16(f);
    u16 u; __builtin_memcpy(&u, &h, 2); return u;
}
__device__ __forceinline__ u32 pk2(float lo, float hi){
    return (u32)f2b(lo) | ((u32)f2b(hi) << 16);
}
__device__ __forceinline__ float b2f(u16 u){
    u32 w = ((u32)u) << 16; float f; __builtin_memcpy(&f, &w, 4); return f;
}

#define PART_STRIDE 8448  // 32q x 128d bf16 O^T (ln*128) + 32 f32 m + 32 f32 l

// S=2048, H=32, HKV=8, G=4, D=128, DIFF_BS=32
// R7: QBLK=64 -> 512-thread / 8-wave blocks (4 heads x 2 q-halves share one
// K/V stage; halves staging+barrier cost per FLOP). Split-KV chunks of 512
// keys. Per-wave compute identical to the R3-verified 32x32 swapped-MFMA core.
// V^T staging redesigned conflict-free: lane = d-row (d&7 spans 0..7 per
// instr), wave owns 8-key column block, uint4 writes (was 16-way-conflicted
// scalar u16 -> bulk of R6's 1.18e7 SQ_LDS_BANK_CONFLICT).
template<bool SPLIT>
__global__ __launch_bounds__(512, 2)
void dllm_attn(const float* __restrict__ Qg, const float* __restrict__ Kg,
               const float* __restrict__ Vg, float* __restrict__ Og,
               char* __restrict__ Wg)
{
    __shared__ alignas(16) char kl[64 * 256];   // K tile bf16 [64][128], XOR swz (k&7)<<4
    __shared__ alignas(16) char vl[128 * 128];  // V^T tile bf16 [128][64], XOR swz (d&7)<<4

    const int bid = blockIdx.x;
    const int kh  = bid & 7;
    int tq2, ci, uu = 0;
    if (SPLIT){
        uu = 79 - (bid >> 3);                   // big tiles first
        if (uu < 8)       { tq2 = uu; ci = 0; }
        else if (uu < 24) { const int x = uu - 8;  tq2 = 8  + (x >> 1); ci = x & 1; }
        else if (uu < 48) { const int x = uu - 24; const int d3 = x / 3; tq2 = 16 + d3; ci = x - 3 * d3; }
        else              { const int x = uu - 48; tq2 = 24 + (x >> 2); ci = x & 3; }
    } else { tq2 = 31 - (bid >> 3); ci = 0; }
    const int ntt = tq2 + 1;                    // 64-key tiles needed by this q-block
    const int t0  = SPLIT ? (ci << 3) : 0;
    const int t1  = SPLIT ? min(t0 + 8, ntt) : ntt;
    const int nch = SPLIT ? ((tq2 >> 3) + 1) : 1;

    const int tid = threadIdx.x;
    const int wv  = tid >> 6;                   // 0..7: (half<<2)|hgrp
    const int ln  = tid & 63;
    const int lq  = ln & 31;
    const int hi  = ln >> 5;
    const int swz = (lq & 7) << 4;
    const int hgrp = wv & 3;
    const int half = wv >> 2;
    const int h   = (kh << 2) + hgrp;
    const int qw0 = (tq2 << 6) + (half << 5);   // wave's q-row base
    const int nvis = qw0 + 32;                  // block-causal visible keys for this wave

    const float QS = 0.088388347648318447f * 1.4426950408889634f; // SCALE*log2(e)
    short8 qf[8];
    {
        const float* qp = Qg + (size_t)(qw0 + lq) * 4096 + h * 128 + hi * 8;
        #pragma unroll
        for (int ds = 0; ds < 8; ++ds){
            const float4 a = *reinterpret_cast<const float4*>(qp + ds * 16);
            const float4 b = *reinterpret_cast<const float4*>(qp + ds * 16 + 4);
            qf[ds] = __builtin_bit_cast(short8,
                make_uint4(pk2(a.x * QS, a.y * QS), pk2(a.z * QS, a.w * QS),
                           pk2(b.x * QS, b.y * QS), pk2(b.z * QS, b.w * QS)));
        }
    }

    f32x16 oa[4];
    #pragma unroll
    for (int i = 0; i < 4; ++i)
        #pragma unroll
        for (int j = 0; j < 16; ++j) oa[i][j] = 0.f;
    float mR = -1e30f, lR = 0.f;

    // staging coords
    const int krow = tid >> 3;                  // 0..63 (key row)
    const int kdc  = tid & 7;                   // 16-float d-chunk
    const int vk0  = wv << 3;                   // wave's 8-key column block
    const int dA   = ln;                        // V^T rows ln and ln+64

    for (int t = t0; t < t1; ++t){
        const int kv0 = t << 6;
        const bool full = (kv0 + 64) <= nvis;   // wave-uniform

        __syncthreads();
        { // ---- stage K -> kl: 4 coalesced float4 loads, 2 uint4 swz writes ----
            const float* kp = Kg + (size_t)(kv0 + krow) * 1024 + (kh << 7) + (kdc << 4);
            const float4 a = *reinterpret_cast<const float4*>(kp);
            const float4 b = *reinterpret_cast<const float4*>(kp + 4);
            const float4 c = *reinterpret_cast<const float4*>(kp + 8);
            const float4 d = *reinterpret_cast<const float4*>(kp + 12);
            const int kb = krow * 256 + (kdc << 5);
            const int key = (krow & 7) << 4;
            *reinterpret_cast<uint4*>(&kl[krow * 256 + ((kdc << 5) ^ key)]) =
                make_uint4(pk2(a.x,a.y), pk2(a.z,a.w), pk2(b.x,b.y), pk2(b.z,b.w));
            *reinterpret_cast<uint4*>(&kl[krow * 256 + (((kdc << 5) + 16) ^ key)]) =
                make_uint4(pk2(c.x,c.y), pk2(c.z,c.w), pk2(d.x,d.y), pk2(d.z,d.w));
            (void)kb;
            // ---- stage V^T -> vl: coalesced row-chunk loads, uint4 writes ----
            const float* vp = Vg + (size_t)(kv0 + vk0) * 1024 + (kh << 7);
            float va[8], vb[8];
            #pragma unroll
            for (int j = 0; j < 8; ++j){
                va[j] = vp[j * 1024 + dA];
                vb[j] = vp[j * 1024 + 64 + dA];
            }
            *reinterpret_cast<uint4*>(&vl[dA * 128 + ((vk0 << 1) ^ ((dA & 7) << 4))]) =
                make_uint4(pk2(va[0],va[1]), pk2(va[2],va[3]),
                           pk2(va[4],va[5]), pk2(va[6],va[7]));
            const int dB = dA + 64;
            *reinterpret_cast<uint4*>(&vl[dB * 128 + ((vk0 << 1) ^ ((dB & 7) << 4))]) =
                make_uint4(pk2(vb[0],vb[1]), pk2(vb[2],vb[3]),
                           pk2(vb[4],vb[5]), pk2(vb[6],vb[7]));
        }
        __syncthreads();

        // ---- QK^T (swapped): S^T[kk][q] ----
        f32x16 s0, s1;
        #pragma unroll
        for (int i = 0; i < 16; ++i){ s0[i] = 0.f; s1[i] = 0.f; }
        __builtin_amdgcn_s_setprio(1);
        #pragma unroll
        for (int ds = 0; ds < 8; ++ds){
            const short8 a0 = *reinterpret_cast<const short8*>(
                &kl[lq * 256 + (((ds << 5) + (hi << 4)) ^ swz)]);
            s0 = __builtin_amdgcn_mfma_f32_32x32x16_bf16(a0, qf[ds], s0, 0, 0, 0);
        }
        if (full){
            #pragma unroll
            for (int ds = 0; ds < 8; ++ds){
                const short8 a1 = *reinterpret_cast<const short8*>(
                    &kl[(32 + lq) * 256 + (((ds << 5) + (hi << 4)) ^ swz)]);
                s1 = __builtin_amdgcn_mfma_f32_32x32x16_bf16(a1, qf[ds], s1, 0, 0, 0);
            }
        }
        __builtin_amdgcn_s_setprio(0);

        // ---- online softmax (lane-local per q=lq) ----
        float p0[16], p1[16];
        float mx = -1e30f;
        #pragma unroll
        for (int r = 0; r < 16; ++r){ p0[r] = s0[r]; mx = fmaxf(mx, s0[r]); }
        if (full){
            #pragma unroll
            for (int r = 0; r < 16; ++r){ p1[r] = s1[r]; mx = fmaxf(mx, s1[r]); }
        }
        mx = fmaxf(mx, __shfl_xor(mx, 32, 64));
        const float mn = fmaxf(mR, mx);
        const float cf = __builtin_exp2f(mR - mn);
        mR = mn;
        float ps = 0.f;
        #pragma unroll
        for (int r = 0; r < 16; ++r){ p0[r] = __builtin_exp2f(p0[r] - mn); ps += p0[r]; }
        if (full){
            #pragma unroll
            for (int r = 0; r < 16; ++r){ p1[r] = __builtin_exp2f(p1[r] - mn); ps += p1[r]; }
        }
        ps += __shfl_xor(ps, 32, 64);
        lR = lR * cf + ps;
        #pragma unroll
        for (int i = 0; i < 4; ++i)
            #pragma unroll
            for (int j = 0; j < 16; ++j) oa[i][j] *= cf;

        // ---- P^T -> bf16 words + partner exchange ----
        u32 pw0[8], px0[8], pw1[8], px1[8];
        #pragma unroll
        for (int rr = 0; rr < 8; ++rr){
            pw0[rr] = pk2(p0[2*rr], p0[2*rr+1]);
            px0[rr] = (u32)__shfl_xor((int)pw0[rr], 32, 64);
        }
        if (full){
            #pragma unroll
            for (int rr = 0; rr < 8; ++rr){
                pw1[rr] = pk2(p1[2*rr], p1[2*rr+1]);
                px1[rr] = (u32)__shfl_xor((int)pw1[rr], 32, 64);
            }
        }

        // ---- build PV B-fragments ----
        short8 pf[4];
        #pragma unroll
        for (int ks = 0; ks < 4; ++ks){
            if (ks < 2 || full){
                const u32* pwt = (ks >> 1) ? pw1 : pw0;
                const u32* pxt = (ks >> 1) ? px1 : px0;
                u32 wb[4];
                #pragma unroll
                for (int w = 0; w < 4; ++w){
                    const int b = (w & 1) + ((ks & 1) << 2);
                    const u32 own = hi ? pwt[b + 2] : pwt[b];
                    const u32 oth = hi ? pxt[b + 2] : pxt[b];
                    wb[w] = (hi == (w >> 1)) ? own : oth;
                }
                pf[ks] = __builtin_bit_cast(short8, make_uint4(wb[0], wb[1], wb[2], wb[3]));
            }
        }

        // ---- PV (swapped): O^T[d][q] += V^T[d][k] * P^T[k][q] ----
        __builtin_amdgcn_s_setprio(1);
        #pragma unroll
        for (int dt = 0; dt < 4; ++dt){
            #pragma unroll
            for (int ks = 0; ks < 4; ++ks){
                if (ks < 2 || full){
                    const short8 vf = *reinterpret_cast<const short8*>(
                        &vl[((dt << 5) + lq) * 128 + (((ks << 5) + (hi << 4)) ^ swz)]);
                    oa[dt] = __builtin_amdgcn_mfma_f32_32x32x16_bf16(vf, pf[ks], oa[dt], 0, 0, 0);
                }
            }
        }
        __builtin_amdgcn_s_setprio(0);
    }

    if (!SPLIT || nch == 1){
        // direct epilogue: O = O^T / l, f32
        const float rl = 1.f / lR;
        float* op = Og + (size_t)(qw0 + lq) * 4096 + (h << 7) + (hi << 2);
        #pragma unroll
        for (int dt = 0; dt < 4; ++dt){
            #pragma unroll
            for (int g2 = 0; g2 < 4; ++g2){
                float4 w4;
                w4.x = oa[dt][4*g2 + 0] * rl;
                w4.y = oa[dt][4*g2 + 1] * rl;
                w4.z = oa[dt][4*g2 + 2] * rl;
                w4.w = oa[dt][4*g2 + 3] * rl;
                *reinterpret_cast<float4*>(op + (dt << 5) + (g2 << 3)) = w4;
            }
        }
    } else {
        // partial epilogue: unnormalized bf16 O^T + (m,l), one record per wave
        const int pu = ((kh * 72 + (uu - 8)) << 3) + wv;
        char* base = Wg + (size_t)pu * PART_STRIDE;
        #pragma unroll
        for (int i = 0; i < 8; ++i){
            const int e0 = i * 8;
            uint4 w4;
            w4.x = pk2(oa[(e0+0)>>4][(e0+0)&15], oa[(e0+1)>>4][(e0+1)&15]);
            w4.y = pk2(oa[(e0+2)>>4][(e0+2)&15], oa[(e0+3)>>4][(e0+3)&15]);
            w4.z = pk2(oa[(e0+4)>>4][(e0+4)&15], oa[(e0+5)>>4][(e0+5)&15]);
            w4.w = pk2(oa[(e0+6)>>4][(e0+6)&15], oa[(e0+7)>>4][(e0+7)&15]);
            *reinterpret_cast<uint4*>(base + ln * 128 + i * 16) = w4;
        }
        if (hi == 0){
            *reinterpret_cast<float*>(base + 8192 + lq * 4) = mR;
            *reinterpret_cast<float*>(base + 8320 + lq * 4) = lR;
        }
    }
}

// Merge: 256 threads/block, one block per (q-head, tq2>=8, half).
// Record layout identical to R6 (verified): byte ln*128 + i*16 + k*4 holds
// (d, d+1), d = 16*i + 8*(k>>1) + 2*(k&1) + 4*(ln>>5).
__global__ __launch_bounds__(256, 2)
void dllm_merge(float* __restrict__ Og, const char* __restrict__ Wg)
{
    const int b    = blockIdx.x;          // [0, 1536)
    const int h    = b & 31;
    const int r    = b >> 5;              // 0..47
    const int tq2  = 8 + (r >> 1);
    const int half = r & 1;
    const int kh = h >> 2, hgrp = h & 3;
    const int wvIdx = (half << 2) | hgrp;
    const int nch = (tq2 >> 3) + 1;       // 2..4
    int cb;
    if (tq2 < 16)      cb = (tq2 - 8) << 1;
    else if (tq2 < 24) cb = 16 + (tq2 - 16) * 3;
    else               cb = 40 + ((tq2 - 24) << 2);

    const int tid = threadIdx.x;
    const int q   = tid >> 3;             // 0..31
    const int s   = tid & 7;              // d0 = 16*s

    const char* bases[4];
    float mv[4], lv[4];
    float M = -1e30f;
    #pragma unroll
    for (int c = 0; c < 4; ++c){
        if (c < nch){
            bases[c] = Wg + (size_t)(((kh * 72 + cb + c) << 3) + wvIdx) * PART_STRIDE;
            mv[c] = *reinterpret_cast<const float*>(bases[c] + 8192 + q * 4);
            lv[c] = *reinterpret_cast<const float*>(bases[c] + 8320 + q * 4);
            M = fmaxf(M, mv[c]);
        }
    }
    uint4 wlo[4], whi[4];
    #pragma unroll
    for (int c = 0; c < 4; ++c){
        if (c < nch){
            wlo[c] = *reinterpret_cast<const uint4*>(bases[c] + q * 128 + s * 16);
            whi[c] = *reinterpret_cast<const uint4*>(bases[c] + (q + 32) * 128 + s * 16);
        }
    }
    float wsum = 0.f;
    float acc[16];
    #pragma unroll
    for (int e = 0; e < 16; ++e) acc[e] = 0.f;
    #pragma unroll
    for (int c = 0; c < 4; ++c){
        if (c < nch){
            const float w = __builtin_exp2f(mv[c] - M);
            wsum += lv[c] * w;
            const u32 wl[4] = {wlo[c].x, wlo[c].y, wlo[c].z, wlo[c].w};
            const u32 wh[4] = {whi[c].x, whi[c].y, whi[c].z, whi[c].w};
            #pragma unroll
            for (int k = 0; k < 4; ++k){
                const int dl = ((k & 1) << 1) + ((k >> 1) << 3);   // 0,2,8,10
                acc[dl + 0] += b2f((u16)(wl[k] & 0xffffu)) * w;
                acc[dl + 1] += b2f((u16)(wl[k] >> 16)) * w;
                acc[dl + 4] += b2f((u16)(wh[k] & 0xffffu)) * w;
                acc[dl + 5] += b2f((u16)(wh[k] >> 16)) * w;
            }
        }
    }
    const float rl = 1.f / wsum;
    float* op = Og + (size_t)((tq2 << 6) + (half << 5) + q) * 4096 + h * 128 + (s << 4);
    #pragma unroll
    for (int g = 0; g < 4; ++g){
        float4 v4;
        v4.x = acc[g*4 + 0] * rl;
        v4.y = acc[g*4 + 1] * rl;
        v4.z = acc[g*4 + 2] * rl;
        v4.w = acc[g*4 + 3] * rl;
        *reinterpret_cast<float4*>(op + (g << 2)) = v4;
    }
}

extern "C" void kernel_launch(void* const* d_in, const int* in_sizes, int n_in,
                              void* d_out, int out_size, void* d_ws, size_t ws_size,
                              hipStream_t stream) {
    const float* Q = (const float*)d_in[0];
    const float* K = (const float*)d_in[1];
    const float* V = (const float*)d_in[2];
    float* O = (float*)d_out;
    const size_t need = (size_t)4608 * PART_STRIDE;   // 38.9 MB of partials
    if (ws_size >= need){
        dllm_attn<true><<<dim3(640), dim3(512), 0, stream>>>(Q, K, V, O, (char*)d_ws);
        dllm_merge<<<dim3(1536), dim3(256), 0, stream>>>(O, (const char*)d_ws);
    } else {
        // fallback: monolithic QBLK=64 path (no workspace)
        dllm_attn<false><<<dim3(256), dim3(512), 0, stream>>>(Q, K, V, O, (char*)d_ws);
    }
}